// Round 13
// baseline (140.982 us; speedup 1.0000x reference)
//
#include <hip/hip_runtime.h>
#include <math.h>

#define NROWS 32768
#define NCODE 1024
#define GAP_THRESH 1.5e-4f  // exact fp32 gap; emulation err ~1e-5, np-ref rounding ~2e-5
#define FLAG_TAG_SHIFT 30   // flags[row]>>30==1 <=> ambiguous (rejects 0xAA poison AND 0)

typedef __attribute__((ext_vector_type(8))) short bf16x8;   // 8 bf16 = 4 VGPRs
typedef __attribute__((ext_vector_type(4))) float f32x4;    // MFMA acc

__device__ __forceinline__ unsigned short bf16_rne(float f) {
    unsigned u = __float_as_uint(f);
    unsigned r = u + 0x7FFFu + ((u >> 16) & 1u);
    return (unsigned short)(r >> 16);
}

// ---------------------------------------------------------------------------
// main: 512 blocks x 512 threads = 64 rows x ALL 1024 codes (r12 shape,
// 41.7 us). CHANGE: prep kernel folded in — each block loads raw fp32 cb
// chunks (128 codes, 32 KB) into regs, converts to split-bf16 frags in-LDS
// (once per block; conversion is independent VALU that fills latency bubbles),
// computes cn4 via quad-shfl. No wsB, no global counters needing init:
//   - ambiguity -> tagged flags (poison/zero-proof)
//   - sumsq     -> per-block sumsqP (plain store)
//   - entropy   -> entPartial per-block rows (always fully written)
//   - ticket=0  -> written here (kernel-boundary visibility for tail)
// ---------------------------------------------------------------------------
__global__ __launch_bounds__(512, 4) void vq_main(
    const float* __restrict__ x, const float* __restrict__ cb,
    float* __restrict__ out, float* __restrict__ entPartial,
    unsigned* __restrict__ flags, float* __restrict__ sumsqP,
    unsigned* __restrict__ ticket)
{
    __shared__ __align__(16) unsigned char Bb[2][32768];
    __shared__ float cn4L[2][128];
    __shared__ unsigned scrE[1024];        // per-block per-code min dist (raw bits)
    __shared__ float mD1[128], mD2[128];   // [row 0..63][half 0..1]
    __shared__ int   mI1[128];
    __shared__ int   tokS[64];
    __shared__ float redS[8];

    const int tid = threadIdx.x;
    const int lane = tid & 63;
    const int wi = tid >> 6;         // 0..7
    const int g = wi >> 1;           // row group 0..3 (16 rows each)
    const int h = wi & 1;            // code half: ct tiles 4h..4h+3
    const int ln15 = lane & 15;
    const int q = lane >> 4;
    const int row0 = blockIdx.x * 64;
    const int rot = blockIdx.x & 7;  // 8 chunks of 128 codes

    if (blockIdx.x == 0 && tid == 0) *ticket = 0u;

    // init scrE to +inf bits
    scrE[tid] = 0x7F800000u;
    scrE[512 + tid] = 0x7F800000u;

    // stage: convert 16 fp32 (one quarter code row) -> hi/lo frags + cn4
    auto stage = [&](int bufIdx, float4 v0, float4 v1, float4 v2, float4 v3) {
        float f[16] = {v0.x,v0.y,v0.z,v0.w, v1.x,v1.y,v1.z,v1.w,
                       v2.x,v2.y,v2.z,v2.w, v3.x,v3.y,v3.z,v3.w};
        float ss = 0.f;
        #pragma unroll
        for (int j = 0; j < 16; j++) ss = fmaf(f[j], f[j], ss);
        ss += __shfl_xor(ss, 1);
        ss += __shfl_xor(ss, 2);        // quad (same code) full partial-sum
        const int lc = tid >> 2, p = tid & 3;
        const int ct = lc >> 4, cl = lc & 15;
        const int half = p >> 1, gp = p & 1;
        unsigned char* tb = Bb[bufIdx] + (ct >> 2)*16384 + (ct & 3)*4096;
        #pragma unroll
        for (int sub = 0; sub < 2; sub++) {
            unsigned short h8[8] __attribute__((aligned(16)));
            unsigned short l8[8] __attribute__((aligned(16)));
            #pragma unroll
            for (int j = 0; j < 8; j++) {
                float ff = f[sub*8 + j];
                unsigned short hi = bf16_rne(ff);
                h8[j] = hi;
                l8[j] = bf16_rne(ff - __uint_as_float((unsigned)hi << 16));
            }
            int off = ((gp*2 + sub)*16 + cl) * 16;
            *(uint4*)(tb + half*1024 + off)        = *(const uint4*)h8;   // q = half
            *(uint4*)(tb + 2048 + half*1024 + off) = *(const uint4*)l8;   // q = 2+half
        }
        if (p == 0) cn4L[bufIdx][lc] = ss + 4.0f;
    };

    // preload chunk 'rot' raw fp32 into regs (coalesced: quad covers one code)
    float4 v0, v1, v2, v3;
    {
        const float4* ls = (const float4*)(cb + ((size_t)rot*128 + (tid>>2))*64 + (tid&3)*16);
        v0 = ls[0]; v1 = ls[1]; v2 = ls[2]; v3 = ls[3];
    }

    // ---- A: 16 rows fp32 -> split-bf16 frags in regs; row norms via shfl ----
    bf16x8 Ah0, Ah1, Al0, Al1;
    float xnm4[4];
    {
        const float* xr = x + (size_t)(row0 + g*16 + ln15) * 64 + q * 8;
        float4 f0 = *(const float4*)xr;
        float4 f1 = *(const float4*)(xr + 4);
        float4 f2 = *(const float4*)(xr + 32);
        float4 f3 = *(const float4*)(xr + 36);
        float fa[8] = {f0.x,f0.y,f0.z,f0.w,f1.x,f1.y,f1.z,f1.w};
        float fb[8] = {f2.x,f2.y,f2.z,f2.w,f3.x,f3.y,f3.z,f3.w};
        unsigned short hh8[8] __attribute__((aligned(16)));
        unsigned short ll8[8] __attribute__((aligned(16)));
        unsigned short h28[8] __attribute__((aligned(16)));
        unsigned short l28[8] __attribute__((aligned(16)));
        float ss = 0.f;
        #pragma unroll
        for (int j = 0; j < 8; j++) {
            ss += fa[j]*fa[j] + fb[j]*fb[j];
            unsigned short hh = bf16_rne(fa[j]);
            hh8[j] = hh; ll8[j] = bf16_rne(fa[j] - __uint_as_float((unsigned)hh << 16));
            hh = bf16_rne(fb[j]);
            h28[j] = hh; l28[j] = bf16_rne(fb[j] - __uint_as_float((unsigned)hh << 16));
        }
        Ah0 = *(const bf16x8*)hh8; Al0 = *(const bf16x8*)ll8;
        Ah1 = *(const bf16x8*)h28; Al1 = *(const bf16x8*)l28;
        ss += __shfl_xor(ss, 16);
        ss += __shfl_xor(ss, 32);            // ||x_row(ln15)||^2
        #pragma unroll
        for (int r = 0; r < 4; r++)
            xnm4[r] = __shfl(ss, (q << 2) | r, 64) - 4.0f;  // xn(row q*4+r) - 4
    }

    // convert+write chunk 'rot' into Bb[0]
    stage(0, v0, v1, v2, v3);

    float d1[4], d2[4];
    int   i1[4];
    #pragma unroll
    for (int r = 0; r < 4; r++) { d1[r] = INFINITY; d2[r] = INFINITY; i1[r] = 0; }

    // ---- chunk loop: 8 chunks x 128 codes (rotated order) ----
    for (int s = 0; s < 8; s++) {
        __syncthreads();   // Bb[s&1]+cn4L[s&1] staged; Bb[nb] free (prev users done)
        const int cb_ = s & 1, nb = (s + 1) & 1;
        const int cphys = (s + rot) & 7;
        if (s < 7) {       // prefetch next raw chunk into regs
            const int cnx = (s + 1 + rot) & 7;
            const float4* ls = (const float4*)(cb + ((size_t)cnx*128 + (tid>>2))*64 + (tid&3)*16);
            v0 = ls[0]; v1 = ls[1]; v2 = ls[2]; v3 = ls[3];
        }
        const unsigned char* buf = Bb[cb_];
        #pragma unroll
        for (int lct = 0; lct < 4; lct++) {
            const int ct = 4*h + lct;                       // 0..7 within 128-code chunk
            const unsigned char* tb = buf + (ct >> 2)*16384 + (ct & 3)*4096;
            bf16x8 Bh0 = *(const bf16x8*)(tb +    0 + lane*16);
            bf16x8 Bh1 = *(const bf16x8*)(tb + 1024 + lane*16);
            bf16x8 Bl0 = *(const bf16x8*)(tb + 2048 + lane*16);
            bf16x8 Bl1 = *(const bf16x8*)(tb + 3072 + lane*16);
            float cn4v = cn4L[cb_][ct*16 + ln15];
            int kid = cphys*128 + ct*16 + ln15;
            f32x4 z = {0.f, 0.f, 0.f, 0.f};
            f32x4 acc0 = __builtin_amdgcn_mfma_f32_16x16x32_bf16(Ah0, Bh0, z, 0, 0, 0);
            f32x4 acc1 = __builtin_amdgcn_mfma_f32_16x16x32_bf16(Ah1, Bh1, z, 0, 0, 0);
            acc0 = __builtin_amdgcn_mfma_f32_16x16x32_bf16(Ah0, Bl0, acc0, 0, 0, 0);
            acc1 = __builtin_amdgcn_mfma_f32_16x16x32_bf16(Ah1, Bl1, acc1, 0, 0, 0);
            acc0 = __builtin_amdgcn_mfma_f32_16x16x32_bf16(Al0, Bh0, acc0, 0, 0, 0);
            acc1 = __builtin_amdgcn_mfma_f32_16x16x32_bf16(Al1, Bh1, acc1, 0, 0, 0);
            float cminv = INFINITY;
            #pragma unroll
            for (int r = 0; r < 4; r++) {
                float sdot = acc0[r] + acc1[r];
                float wv = fmaf(sdot, -2.0f, cn4v);   // 4 + cn - 2s  (>0)
                bool lt = wv < d1[r];
                d2[r] = lt ? d1[r] : fminf(d2[r], wv);
                i1[r] = lt ? kid   : i1[r];
                d1[r] = lt ? wv    : d1[r];
                cminv = fminf(cminv, wv + xnm4[r]);   // full dist (entropy)
            }
            cminv = fminf(cminv, __shfl_xor(cminv, 16));
            cminv = fminf(cminv, __shfl_xor(cminv, 32));   // min over wave's 16 rows
            if (q == lct) atomicMin(&scrE[kid], __float_as_uint(cminv));
        }
        if (s < 7) stage(nb, v0, v1, v2, v3);   // convert+write next chunk
    }
    __syncthreads();   // scrE complete; all compute done

    // ---- butterfly exact top-2 merge across the 16 code-column lanes ----
    #pragma unroll
    for (int d = 1; d < 16; d <<= 1) {
        #pragma unroll
        for (int r = 0; r < 4; r++) {
            float od1 = __shfl_xor(d1[r], d);
            int   oi1 = __shfl_xor(i1[r], d);
            float od2 = __shfl_xor(d2[r], d);
            bool take = (od1 < d1[r]) || (od1 == d1[r] && oi1 < i1[r]);
            float loser = take ? d1[r] : od1;
            d2[r] = fminf(fminf(d2[r], od2), loser);
            d1[r] = take ? od1 : d1[r];
            i1[r] = take ? oi1 : i1[r];
        }
    }
    if (ln15 == 0) {
        #pragma unroll
        for (int r = 0; r < 4; r++) {
            int idx = (g*16 + q*4 + r) * 2 + h;
            mD1[idx] = d1[r]; mI1[idx] = i1[r]; mD2[idx] = d2[r];
        }
    }
    __syncthreads();   // per-half candidates staged

    // ---- exact cross-half merge -> token + tagged ambiguity flag ----
    if (tid < 64) {
        float a1 = mD1[tid*2],   b1 = mD1[tid*2+1];
        int   ai = mI1[tid*2],   bi = mI1[tid*2+1];
        float a2 = mD2[tid*2],   b2 = mD2[tid*2+1];
        bool ta = (a1 < b1) || (a1 == b1 && ai < bi);
        float D1 = ta ? a1 : b1;
        int   I1 = ta ? ai : bi;
        float D2 = ta ? fminf(a2, b1) : fminf(b2, a1);
        tokS[tid] = I1;
        if (D2 - D1 < GAP_THRESH)
            flags[row0 + tid] = (1u << FLAG_TAG_SHIFT) | (unsigned)I1;
    }

    // ---- entropy partials: coalesced per-block row (always fully written) ----
    entPartial[(size_t)blockIdx.x * 1024 + tid]       = __uint_as_float(scrE[tid]);
    entPartial[(size_t)blockIdx.x * 1024 + 512 + tid] = __uint_as_float(scrE[512 + tid]);
    __syncthreads();   // tokS ready

    // ---- emb gather + sumsq -> sumsqP[block] ----
    {
        float acc2 = 0.f;
        #pragma unroll
        for (int uu = 0; uu < 2; uu++) {
            int u = uu*512 + tid;
            int row = u >> 4, c4 = u & 15;
            int tok = tokS[row];
            float4 c = ((const float4*)(cb + (size_t)tok*64))[c4];
            float4 xx = ((const float4*)(x + (size_t)(row0 + row)*64))[c4];
            ((float4*)(out + (size_t)(row0 + row)*64))[c4] = c;
            float dx = c.x-xx.x, dy = c.y-xx.y, dz = c.z-xx.z, dw = c.w-xx.w;
            acc2 += dx*dx + dy*dy + dz*dz + dw*dw;
        }
        #pragma unroll
        for (int o = 32; o > 0; o >>= 1) acc2 += __shfl_down(acc2, o);
        if (lane == 0) redS[wi] = acc2;
        __syncthreads();
        if (tid == 0) {
            float t = 0.f;
            #pragma unroll
            for (int w = 0; w < 8; w++) t += redS[w];
            sumsqP[blockIdx.x] = t;
        }
    }
}

// ---------------------------------------------------------------------------
// tail: 64 blocks x 256 threads.
// (A) coalesced entropy reduce: block=(rowGroup rg=b>>4, codeGroup cgp=b&15);
//     wave reads 64 consecutive codes x 32 block-rows -> partial2[4][1024].
// (B) scan flags (512 rows/block), fp64 fixup of tagged rows, delta->deltaP.
// (C) last-ticket block: min over 4 rowGroups + sums -> loss.
// ---------------------------------------------------------------------------
__global__ __launch_bounds__(256) void vq_tail(
    const float* __restrict__ x, const float* __restrict__ cb,
    float* __restrict__ out, const float* __restrict__ entPartial,
    const unsigned* __restrict__ flags, const float* __restrict__ sumsqP,
    float* __restrict__ deltaP, float* __restrict__ partial2,
    unsigned* __restrict__ ticket, float* __restrict__ out_loss)
{
    __shared__ double xs[64];
    __shared__ double bd[256];
    __shared__ int    bi[256];
    __shared__ float  scrR[256];
    __shared__ int    listRow[32], listTok[32];
    __shared__ int    lcnt;
    __shared__ double deltaS;
    __shared__ unsigned lastS;
    __shared__ float redS[4], redS2[4];

    const int tid = threadIdx.x;
    const int lane = tid & 63;
    const int w = tid >> 6;
    const int b = blockIdx.x;

    if (tid == 0) { lcnt = 0; deltaS = 0.0; }

    // ---- A: entropy 512 blocks -> 4 rowGroups (coalesced 256B reads) ----
    {
        int rg = b >> 4, cgp = b & 15;
        float m = INFINITY;
        #pragma unroll 8
        for (int i = 0; i < 32; i++)
            m = fminf(m, entPartial[(size_t)(rg*128 + w*32 + i)*1024 + cgp*64 + lane]);
        scrR[w*64 + lane] = m;
    }
    __syncthreads();
    if (w == 0) {
        float m = fminf(fminf(scrR[lane], scrR[64+lane]),
                        fminf(scrR[128+lane], scrR[192+lane]));
        partial2[(size_t)(b >> 4)*1024 + (b & 15)*64 + lane] = m;
    }

    // ---- B: scan tagged flags, compact, fp64 fixup ----
    #pragma unroll
    for (int u = 0; u < 2; u++) {
        int row = b*512 + u*256 + tid;
        unsigned f = flags[row];
        if ((f >> FLAG_TAG_SHIFT) == 1u) {     // rejects 0xAA poison (0b10) and 0
            int idx = atomicAdd(&lcnt, 1);
            if (idx < 32) { listRow[idx] = row; listTok[idx] = (int)(f & 1023u); }
        }
    }
    __syncthreads();
    int nfix = lcnt < 32 ? lcnt : 32;
    for (int i = 0; i < nfix; i++) {
        int row = listRow[i], oldk = listTok[i];
        __syncthreads();
        if (tid < 64) xs[tid] = (double)x[(size_t)row*64 + tid];
        __syncthreads();
        double xn = 0.0;
        #pragma unroll 8
        for (int d = 0; d < 64; d++) xn += xs[d]*xs[d];
        double best = INFINITY; int bk = 1 << 30;
        #pragma unroll
        for (int j = 0; j < 4; j++) {
            int k = j*256 + tid;
            const float4* c4 = (const float4*)(cb + (size_t)k*64);
            double dot = 0.0, cn2 = 0.0;
            #pragma unroll
            for (int t = 0; t < 16; t++) {
                float4 cv = c4[t];
                double cx = (double)cv.x, cy = (double)cv.y, cz = (double)cv.z, cw = (double)cv.w;
                dot += xs[t*4+0]*cx + xs[t*4+1]*cy + xs[t*4+2]*cz + xs[t*4+3]*cw;
                cn2 += cx*cx + cy*cy + cz*cz + cw*cw;
            }
            double dist = (xn - 2.0*dot) + cn2;
            if (dist < best || (dist == best && k < bk)) { best = dist; bk = k; }
        }
        bd[tid] = best; bi[tid] = bk;
        __syncthreads();
        for (int s = 128; s > 0; s >>= 1) {
            if (tid < s) {
                double od = bd[tid+s]; int ok = bi[tid+s];
                if (od < bd[tid] || (od == bd[tid] && ok < bi[tid])) { bd[tid] = od; bi[tid] = ok; }
            }
            __syncthreads();
        }
        int bestk = bi[0];
        if (bestk != oldk) {
            double part = 0.0;
            if (tid < 64) {
                float cn = cb[(size_t)bestk*64 + tid];
                float co = cb[(size_t)oldk*64 + tid];
                out[(size_t)row*64 + tid] = cn;
                double dn = (double)cn - xs[tid];
                double dl = (double)co - xs[tid];
                part = dn*dn - dl*dl;
            }
            __syncthreads();
            bd[tid] = part;
            __syncthreads();
            for (int s = 128; s > 0; s >>= 1) {
                if (tid < s) bd[tid] += bd[tid+s];
                __syncthreads();
            }
            if (tid == 0) deltaS += bd[0];
        }
    }
    __syncthreads();
    if (tid == 0) deltaP[b] = (float)deltaS;   // always written

    // ---- C: last block assembles the loss ----
    __syncthreads();
    if (tid == 0) {
        __threadfence();
        lastS = (atomicAdd(ticket, 1u) == 63u) ? 1u : 0u;
    }
    __syncthreads();
    if (lastS) {
        __threadfence();
        volatile const float* sp = sumsqP;
        volatile const float* dp = deltaP;
        volatile const float* p2 = partial2;
        float sq = sp[tid] + sp[256 + tid] + ((tid < 64) ? dp[tid] : 0.f);
        float es = 0.f;
        #pragma unroll
        for (int jj = 0; jj < 4; jj++) {
            int c = jj*256 + tid;
            es += fminf(fminf(p2[c], p2[1024 + c]), fminf(p2[2048 + c], p2[3072 + c]));
        }
        #pragma unroll
        for (int o = 32; o > 0; o >>= 1) { sq += __shfl_down(sq, o); es += __shfl_down(es, o); }
        if (lane == 0) { redS[w] = sq; redS2[w] = es; }
        __syncthreads();
        if (tid == 0) {
            float S = redS[0] + redS[1] + redS[2] + redS[3];
            float E = redS2[0] + redS2[1] + redS2[2] + redS2[3];
            out_loss[0] = 1.25f * (S / 2097152.0f) + 0.1f * (E / 1024.0f);
        }
    }
}

extern "C" void kernel_launch(void* const* d_in, const int* in_sizes, int n_in,
                              void* d_out, int out_size, void* d_ws, size_t ws_size,
                              hipStream_t stream) {
    const float* x  = (const float*)d_in[0];   // [32768, 64]
    const float* cb = (const float*)d_in[1];   // [1024, 64]
    float* out = (float*)d_out;                // [0,2097152): emb; [2097152]: loss

    char* ws = (char*)d_ws;
    unsigned* ticket     = (unsigned*)ws;                 // @0 (init by main)
    float*    sumsqP     = (float*)(ws + 1024);           // 2 KB  [512]
    float*    deltaP     = (float*)(ws + 4096);           // 256 B [64]
    unsigned* flags      = (unsigned*)(ws + 8192);        // 128 KB [32768] tagged
    float*    partial2   = (float*)(ws + 139264);         // 16 KB [4][1024]
    float*    entPartial = (float*)(ws + 262144);         // 2 MB  [512][1024]

    vq_main<<<512, 512, 0, stream>>>(x, cb, out, entPartial, flags, sumsqP, ticket);
    vq_tail<<<64,  256, 0, stream>>>(x, cb, out, entPartial, flags, sumsqP, deltaP,
                                     partial2, ticket, out + 2097152);
}

// Round 14
// 114.393 us; speedup vs baseline: 1.2324x; 1.2324x over previous
//
#include <hip/hip_runtime.h>
#include <math.h>

#define NROWS 32768
#define NCODE 1024
#define AMB_CAP 8192
#define GAP_THRESH 1.5e-4f  // exact fp32 gap; emulation err ~1e-5, np-ref rounding ~2e-5

typedef __attribute__((ext_vector_type(8))) short bf16x8;   // 8 bf16 = 4 VGPRs
typedef __attribute__((ext_vector_type(4))) float f32x4;    // MFMA acc

__device__ __forceinline__ unsigned short bf16_rne(float f) {
    unsigned u = __float_as_uint(f);
    unsigned r = u + 0x7FFFu + ((u >> 16) & 1u);
    return (unsigned short)(r >> 16);
}

typedef const __attribute__((address_space(1))) unsigned GU;
typedef __attribute__((address_space(3))) unsigned LU;
__device__ __forceinline__ void gl_lds16(const void* g, void* l) {
    __builtin_amdgcn_global_load_lds((GU*)g, (LU*)l, 16, 0, 0);
}
__device__ __forceinline__ void gl_lds4(const void* g, void* l) {
    __builtin_amdgcn_global_load_lds((GU*)g, (LU*)l, 4, 0, 0);
}

// ---------------------------------------------------------------------------
// prep: cn4 = ||c||^2+4, minK=+inf bits, zero counter/gsumsq/ticket,
// codebook -> frag-major split-bf16 (wsB). 16 blocks x 64 codes. (r12 verbatim)
// ---------------------------------------------------------------------------
__global__ __launch_bounds__(64) void vq_prep(
    const float* __restrict__ cb, float* __restrict__ cn4,
    unsigned* __restrict__ minK, unsigned* __restrict__ counter,
    float* __restrict__ gsumsq, unsigned* __restrict__ ticket,
    unsigned short* __restrict__ wsB)
{
    int c = blockIdx.x * 64 + threadIdx.x;
    if (c == 0) { *counter = 0u; *gsumsq = 0.f; *ticket = 0u; }
    float v[64];
    const float4* src = (const float4*)(cb + (size_t)c * 64);
    float s = 0.f;
    #pragma unroll
    for (int i = 0; i < 16; i++) {
        float4 t = src[i];
        v[i*4+0] = t.x; v[i*4+1] = t.y; v[i*4+2] = t.z; v[i*4+3] = t.w;
        s += t.x*t.x + t.y*t.y + t.z*t.z + t.w*t.w;
    }
    cn4[c] = s + 4.0f;
    minK[c] = 0x7F800000u;   // +inf bits (all dists > 0 -> raw-bit order ok)
    int cc = c >> 6, ct = (c >> 4) & 3, cl = c & 15;
    #pragma unroll
    for (int q = 0; q < 4; q++) {
        int half = q & 1, lo = q >> 1;
        #pragma unroll
        for (int g = 0; g < 4; g++) {
            unsigned short u8[8] __attribute__((aligned(16)));
            #pragma unroll
            for (int j = 0; j < 8; j++) {
                float f = v[half*32 + g*8 + j];
                unsigned short h = bf16_rne(f);
                if (lo) h = bf16_rne(f - __uint_as_float((unsigned)h << 16));
                u8[j] = h;
            }
            size_t off = (size_t)cc * 8192 + ct * 2048 + q * 512 + (g * 16 + cl) * 8;
            *(uint4*)(wsB + off) = *(const uint4*)u8;
        }
    }
}

// ---------------------------------------------------------------------------
// main: 512 blocks x 512 threads = 64 rows x ALL 1024 codes; 8 chunks of 128
// codes double-buffered via global_load_lds(16B). (r12 verbatim, 41.7 us)
// ---------------------------------------------------------------------------
__global__ __launch_bounds__(512, 4) void vq_main(
    const float* __restrict__ x, const float* __restrict__ cb,
    const unsigned short* __restrict__ wsB, const float* __restrict__ cn4,
    float* __restrict__ out, unsigned* __restrict__ minK,
    unsigned* __restrict__ counter, int* __restrict__ amb,
    float* __restrict__ gsumsq)
{
    __shared__ __align__(16) unsigned char Bb[2][32768];
    __shared__ float cn4L[2][128];
    __shared__ unsigned scrE[1024];        // per-block per-code min dist (raw bits)
    __shared__ float mD1[128], mD2[128];   // [row 0..63][half 0..1]
    __shared__ int   mI1[128];
    __shared__ int   tokS[64];
    __shared__ float redS[8];

    const int tid = threadIdx.x;
    const int lane = tid & 63;
    const int wi = tid >> 6;         // 0..7
    const int g = wi >> 1;           // row group 0..3 (16 rows each)
    const int h = wi & 1;            // code half: ct tiles 4h..4h+3
    const int ln15 = lane & 15;
    const int q = lane >> 4;
    const int row0 = blockIdx.x * 64;
    const int rot = blockIdx.x & 7;  // 8 chunks of 128 codes

    // init scrE to +inf bits
    scrE[tid] = 0x7F800000u;
    scrE[512 + tid] = 0x7F800000u;

    // preload physical chunk 'rot' (B 32KB + cn4 128) straight into LDS
    const char* wsBb = (const char*)wsB;
    {
        int wbase = (tid & ~63) * 16;   // wave-uniform LDS base
        #pragma unroll
        for (int i = 0; i < 4; i++)
            gl_lds16(wsBb + (size_t)rot*32768 + (i*512 + tid)*16,
                     (void*)&Bb[0][i*8192 + wbase]);
        if (wi == 0) {
            gl_lds4(cn4 + rot*128 + lane,      (void*)&cn4L[0][0]);
            gl_lds4(cn4 + rot*128 + 64 + lane, (void*)&cn4L[0][64]);
        }
    }

    // ---- A: 16 rows fp32 -> split-bf16 frags in regs; row norms via shfl ----
    bf16x8 Ah0, Ah1, Al0, Al1;
    float xnm4[4];
    {
        const float* xr = x + (size_t)(row0 + g*16 + ln15) * 64 + q * 8;
        float4 f0 = *(const float4*)xr;
        float4 f1 = *(const float4*)(xr + 4);
        float4 f2 = *(const float4*)(xr + 32);
        float4 f3 = *(const float4*)(xr + 36);
        float fa[8] = {f0.x,f0.y,f0.z,f0.w,f1.x,f1.y,f1.z,f1.w};
        float fb[8] = {f2.x,f2.y,f2.z,f2.w,f3.x,f3.y,f3.z,f3.w};
        unsigned short hh8[8] __attribute__((aligned(16)));
        unsigned short ll8[8] __attribute__((aligned(16)));
        unsigned short h28[8] __attribute__((aligned(16)));
        unsigned short l28[8] __attribute__((aligned(16)));
        float ss = 0.f;
        #pragma unroll
        for (int j = 0; j < 8; j++) {
            ss += fa[j]*fa[j] + fb[j]*fb[j];
            unsigned short hh = bf16_rne(fa[j]);
            hh8[j] = hh; ll8[j] = bf16_rne(fa[j] - __uint_as_float((unsigned)hh << 16));
            hh = bf16_rne(fb[j]);
            h28[j] = hh; l28[j] = bf16_rne(fb[j] - __uint_as_float((unsigned)hh << 16));
        }
        Ah0 = *(const bf16x8*)hh8; Al0 = *(const bf16x8*)ll8;
        Ah1 = *(const bf16x8*)h28; Al1 = *(const bf16x8*)l28;
        ss += __shfl_xor(ss, 16);
        ss += __shfl_xor(ss, 32);            // ||x_row(ln15)||^2
        #pragma unroll
        for (int r = 0; r < 4; r++)
            xnm4[r] = __shfl(ss, (q << 2) | r, 64) - 4.0f;  // xn(row q*4+r) - 4
    }

    float d1[4], d2[4];
    int   i1[4];
    #pragma unroll
    for (int r = 0; r < 4; r++) { d1[r] = INFINITY; d2[r] = INFINITY; i1[r] = 0; }

    // ---- chunk loop: 8 chunks x 128 codes (rotated order) ----
    for (int s = 0; s < 8; s++) {
        __syncthreads();   // drains prefetch: buf[s&1]+cn4L[s&1] ready; buf[nb] free
        const int cb_ = s & 1, nb = (s + 1) & 1;
        const int cphys = (s + rot) & 7;
        if (s < 7) {
            const int cnx = (s + 1 + rot) & 7;
            int wbase = (tid & ~63) * 16;
            #pragma unroll
            for (int i = 0; i < 4; i++)
                gl_lds16(wsBb + (size_t)cnx*32768 + (i*512 + tid)*16,
                         (void*)&Bb[nb][i*8192 + wbase]);
            if (wi == 0) {
                gl_lds4(cn4 + cnx*128 + lane,      (void*)&cn4L[nb][0]);
                gl_lds4(cn4 + cnx*128 + 64 + lane, (void*)&cn4L[nb][64]);
            }
        }
        const unsigned char* buf = Bb[cb_];
        #pragma unroll
        for (int lct = 0; lct < 4; lct++) {
            const int ct = 4*h + lct;                       // 0..7 within 128-code chunk
            const unsigned char* tb = buf + (ct >> 2)*16384 + (ct & 3)*4096;
            bf16x8 Bh0 = *(const bf16x8*)(tb +    0 + lane*16);
            bf16x8 Bh1 = *(const bf16x8*)(tb + 1024 + lane*16);
            bf16x8 Bl0 = *(const bf16x8*)(tb + 2048 + lane*16);
            bf16x8 Bl1 = *(const bf16x8*)(tb + 3072 + lane*16);
            float cn4v = cn4L[cb_][ct*16 + ln15];
            int kid = cphys*128 + ct*16 + ln15;
            f32x4 z = {0.f, 0.f, 0.f, 0.f};
            f32x4 acc0 = __builtin_amdgcn_mfma_f32_16x16x32_bf16(Ah0, Bh0, z, 0, 0, 0);
            f32x4 acc1 = __builtin_amdgcn_mfma_f32_16x16x32_bf16(Ah1, Bh1, z, 0, 0, 0);
            acc0 = __builtin_amdgcn_mfma_f32_16x16x32_bf16(Ah0, Bl0, acc0, 0, 0, 0);
            acc1 = __builtin_amdgcn_mfma_f32_16x16x32_bf16(Ah1, Bl1, acc1, 0, 0, 0);
            acc0 = __builtin_amdgcn_mfma_f32_16x16x32_bf16(Al0, Bh0, acc0, 0, 0, 0);
            acc1 = __builtin_amdgcn_mfma_f32_16x16x32_bf16(Al1, Bh1, acc1, 0, 0, 0);
            float cminv = INFINITY;
            #pragma unroll
            for (int r = 0; r < 4; r++) {
                float sdot = acc0[r] + acc1[r];
                float wv = fmaf(sdot, -2.0f, cn4v);   // 4 + cn - 2s  (>0)
                bool lt = wv < d1[r];
                d2[r] = lt ? d1[r] : fminf(d2[r], wv);
                i1[r] = lt ? kid   : i1[r];
                d1[r] = lt ? wv    : d1[r];
                cminv = fminf(cminv, wv + xnm4[r]);   // full dist (entropy)
            }
            cminv = fminf(cminv, __shfl_xor(cminv, 16));
            cminv = fminf(cminv, __shfl_xor(cminv, 32));   // min over wave's 16 rows
            if (q == lct) atomicMin(&scrE[kid], __float_as_uint(cminv));
        }
    }
    __syncthreads();   // scrE complete; all compute done

    // ---- butterfly exact top-2 merge across the 16 code-column lanes ----
    #pragma unroll
    for (int d = 1; d < 16; d <<= 1) {
        #pragma unroll
        for (int r = 0; r < 4; r++) {
            float od1 = __shfl_xor(d1[r], d);
            int   oi1 = __shfl_xor(i1[r], d);
            float od2 = __shfl_xor(d2[r], d);
            bool take = (od1 < d1[r]) || (od1 == d1[r] && oi1 < i1[r]);
            float loser = take ? d1[r] : od1;
            d2[r] = fminf(fminf(d2[r], od2), loser);
            d1[r] = take ? od1 : d1[r];
            i1[r] = take ? oi1 : i1[r];
        }
    }
    if (ln15 == 0) {
        #pragma unroll
        for (int r = 0; r < 4; r++) {
            int idx = (g*16 + q*4 + r) * 2 + h;
            mD1[idx] = d1[r]; mI1[idx] = i1[r]; mD2[idx] = d2[r];
        }
    }
    __syncthreads();   // per-half candidates staged

    // ---- exact cross-half merge -> token + ambiguity (1 thread/row) ----
    if (tid < 64) {
        float a1 = mD1[tid*2],   b1 = mD1[tid*2+1];
        int   ai = mI1[tid*2],   bi = mI1[tid*2+1];
        float a2 = mD2[tid*2],   b2 = mD2[tid*2+1];
        bool ta = (a1 < b1) || (a1 == b1 && ai < bi);
        float D1 = ta ? a1 : b1;
        int   I1 = ta ? ai : bi;
        float D2 = ta ? fminf(a2, b1) : fminf(b2, a1);
        tokS[tid] = I1;
        if (D2 - D1 < GAP_THRESH) {
            unsigned idx = atomicAdd(counter, 1u);
            if (idx < AMB_CAP) { amb[2*idx] = row0 + tid; amb[2*idx+1] = I1; }
        }
    }

    // ---- entropy: filtered global atomicMin ----
    {
        unsigned u0 = scrE[tid];
        if (u0 < minK[tid]) atomicMin(&minK[tid], u0);          // race benign: monotone
        unsigned u1 = scrE[512 + tid];
        if (u1 < minK[512 + tid]) atomicMin(&minK[512 + tid], u1);
    }
    __syncthreads();   // tokS ready

    // ---- emb gather + sumsq (512 threads x 2 float4 = 64 rows x 16) ----
    {
        float acc2 = 0.f;
        #pragma unroll
        for (int uu = 0; uu < 2; uu++) {
            int u = uu*512 + tid;
            int row = u >> 4, c4 = u & 15;
            int tok = tokS[row];
            float4 c = ((const float4*)(cb + (size_t)tok*64))[c4];
            float4 xx = ((const float4*)(x + (size_t)(row0 + row)*64))[c4];
            ((float4*)(out + (size_t)(row0 + row)*64))[c4] = c;
            float dx = c.x-xx.x, dy = c.y-xx.y, dz = c.z-xx.z, dw = c.w-xx.w;
            acc2 += dx*dx + dy*dy + dz*dz + dw*dw;
        }
        #pragma unroll
        for (int o = 32; o > 0; o >>= 1) acc2 += __shfl_down(acc2, o);
        if (lane == 0) redS[wi] = acc2;
        __syncthreads();
        if (tid == 0) {
            float t = 0.f;
            #pragma unroll
            for (int w = 0; w < 8; w++) t += redS[w];
            atomicAdd(gsumsq, t);
        }
    }
}

// ---------------------------------------------------------------------------
// tail: 64 blocks. (A) fp64 fixup — NOW with cb staged through LDS in 4
// coalesced 64-KB batches (r13 diagnosis: the old per-thread float4 walk
// touched 64 cache lines per wave-load -> ~16k line-requests/row -> the
// recurring ~40-55 us tail floor). LDS reads use +tid rotation (2-way banks).
// (B) last-ticket block: sum minK + loss. (unchanged from r12)
// ---------------------------------------------------------------------------
__global__ __launch_bounds__(256) void vq_tail(
    const float* __restrict__ x, const float* __restrict__ cb,
    float* __restrict__ out, const unsigned* __restrict__ counter,
    const int* __restrict__ amb, float* __restrict__ gsumsq,
    unsigned* __restrict__ ticket, const unsigned* __restrict__ minK,
    float* __restrict__ out_loss)
{
    __shared__ __align__(16) float cbS[16384];   // 64 KB: 256 codes x 64 dims
    __shared__ double xs[64];
    __shared__ double bd[256];
    __shared__ int    bi[256];
    __shared__ unsigned lastS;
    __shared__ float redS[4];

    const int tid = threadIdx.x;

    // ---- A: fp64 re-decision for ambiguous rows (coalesced cb staging) ----
    unsigned cnt = *counter; if (cnt > AMB_CAP) cnt = AMB_CAP;
    for (unsigned i = blockIdx.x; i < cnt; i += gridDim.x) {
        int row = amb[2*i], oldk = amb[2*i+1];
        __syncthreads();
        if (tid < 64) xs[tid] = (double)x[(size_t)row*64 + tid];
        __syncthreads();
        double xn = 0.0;
        #pragma unroll 8
        for (int d = 0; d < 64; d++) xn += xs[d]*xs[d];
        double best = INFINITY; int bk = 1 << 30;
        for (int b = 0; b < 4; b++) {           // 256 codes per batch
            __syncthreads();                    // cbS free for reuse
            #pragma unroll
            for (int k = 0; k < 16; k++)        // 64 KB coalesced: 16 float4/thread
                ((float4*)cbS)[k*256 + tid] = ((const float4*)cb)[b*4096 + k*256 + tid];
            __syncthreads();
            int kcode = b*256 + tid;
            const int t6 = tid & 63;
            double dot = 0.0, cn2 = 0.0;
            #pragma unroll 8
            for (int dd = 0; dd < 64; dd++) {
                int d = (dd + t6) & 63;         // rotation: 2 lanes/bank (free)
                double cv = (double)cbS[tid*64 + d];
                dot = fma(xs[d], cv, dot);
                cn2 = fma(cv, cv, cn2);
            }
            double dist = (xn - 2.0*dot) + cn2;
            if (dist < best || (dist == best && kcode < bk)) { best = dist; bk = kcode; }
        }
        bd[tid] = best; bi[tid] = bk;
        __syncthreads();
        for (int s = 128; s > 0; s >>= 1) {
            if (tid < s) {
                double od = bd[tid+s]; int ok = bi[tid+s];
                if (od < bd[tid] || (od == bd[tid] && ok < bi[tid])) { bd[tid] = od; bi[tid] = ok; }
            }
            __syncthreads();
        }
        int bestk = bi[0];
        if (bestk != oldk) {
            double part = 0.0;
            if (tid < 64) {
                float cn = cb[(size_t)bestk*64 + tid];
                float co = cb[(size_t)oldk*64 + tid];
                out[(size_t)row*64 + tid] = cn;
                double dn = (double)cn - xs[tid];
                double dl = (double)co - xs[tid];
                part = dn*dn - dl*dl;
            }
            __syncthreads();
            bd[tid] = part;
            __syncthreads();
            for (int s = 128; s > 0; s >>= 1) {
                if (tid < s) bd[tid] += bd[tid+s];
                __syncthreads();
            }
            if (tid == 0) atomicAdd(gsumsq, (float)bd[0]);
        }
    }

    // ---- B: last block assembles the loss ----
    __syncthreads();
    if (tid == 0) {
        __threadfence();
        lastS = (atomicAdd(ticket, 1u) == 63u) ? 1u : 0u;
    }
    __syncthreads();
    if (lastS) {
        __threadfence();
        float s = 0.f;
        #pragma unroll
        for (int jj = 0; jj < 4; jj++)
            s += __uint_as_float(minK[jj*256 + tid]);   // raw bits of positive dists
        #pragma unroll
        for (int o = 32; o > 0; o >>= 1) s += __shfl_down(s, o);
        if ((tid & 63) == 0) redS[tid >> 6] = s;
        __syncthreads();
        if (tid == 0) {
            float gs = atomicAdd(gsumsq, 0.0f);         // coherent device-scope read
            float tot = redS[0] + redS[1] + redS[2] + redS[3];
            out_loss[0] = 1.25f * (gs / 2097152.0f) + 0.1f * (tot / 1024.0f);
        }
    }
}

extern "C" void kernel_launch(void* const* d_in, const int* in_sizes, int n_in,
                              void* d_out, int out_size, void* d_ws, size_t ws_size,
                              hipStream_t stream) {
    const float* x  = (const float*)d_in[0];   // [32768, 64]
    const float* cb = (const float*)d_in[1];   // [1024, 64]
    float* out = (float*)d_out;                // [0,2097152): emb; [2097152]: loss

    char* ws = (char*)d_ws;
    unsigned*       counter = (unsigned*)ws;                    // @0
    float*          gsumsq  = (float*)(ws + 4);                 // @4
    unsigned*       ticket  = (unsigned*)(ws + 8);              // @8
    float*          cn4     = (float*)(ws + 1024);              // 4 KB
    unsigned*       minK    = (unsigned*)(ws + 8192);           // 4 KB
    int*            amb     = (int*)(ws + 16384);               // 64 KB
    unsigned short* wsB     = (unsigned short*)(ws + 131072);   // 256 KB

    vq_prep<<<16,  64,  0, stream>>>(cb, cn4, minK, counter, gsumsq, ticket, wsB);
    vq_main<<<512, 512, 0, stream>>>(x, cb, wsB, cn4, out, minK, counter, amb, gsumsq);
    vq_tail<<<64,  256, 0, stream>>>(x, cb, out, counter, amb, gsumsq, ticket, minK,
                                     out + 2097152);
}